// Round 12
// baseline (1551.010 us; speedup 1.0000x reference)
//
#include <hip/hip_runtime.h>
#include <math.h>

// BN(ch=T) -> LSTM(1->64) -> LSTM(64->64) -> FC+GELU.  B=262144 T=15 H=64.
// v12: v11 with M=64 rows per block (was 32): halves per-row barrier/loop/
//      staging overhead. Same grid 512, same (256,2) allocator regime, same
//      1-barrier-per-t parity scheme, same exp2-domain gates (builtin exp2 —
//      the v10 raw-asm trans hazard is the documented failure mode).
//      Register audit: frags 96 + acc 64 + c 32 + misc ~30 = ~222 < 256.
//      Decisive tell if allocator demotes frags: FETCH_SIZE balloons.
//
// ws float offsets:
//   WS_SS    0     scale[15]@+0, shift[15]@+16
//   WS_B0    32    scaled b_ih0+b_hh0 [256]
//   WS_B1    288   scaled b_ih1+b_hh1 [256]
//   WS_FCT   1024  fcT[u][o] fp32 [64][64]  (unscaled)
//   WS_STATS 5200  bn sums[15]@+0, sqsums[15]@+16
//   WS_BF    8192  bf16 B-fragments (gate-scaled): 96 chunks x 512 ushort
//     chunk<32:  L0 (w_hh0^T):  ks=chunk>>4 (K=64: 2), nt=chunk&15
//     chunk>=32: L1 ([w_ih1;w_hh1]^T): ks=(chunk-32)>>4 (K=128: 4), nt=&15
//     elem(lane,j) = B[k=32*ks+8*(lane>>4)+j][n=16*nt+(lane&15)]

typedef __attribute__((ext_vector_type(8))) short short8;
typedef __attribute__((ext_vector_type(4))) float f32x4;

namespace {
constexpr int kB = 262144;
constexpr int kT = 15;
constexpr int kM = 64;            // rows per block
constexpr int kTiles = kB / kM;   // 4096
constexpr int kGrid = 512;        // 2 blocks per CU; 8 tiles per block
constexpr int WS_SS = 0;
constexpr int WS_B0 = 32;
constexpr int WS_B1 = 288;
constexpr int WS_FCT = 1024;
constexpr int WS_STATS = 5200;
constexpr int WS_BF = 8192;
}  // namespace

#if __has_builtin(__builtin_amdgcn_exp2f)
__device__ __forceinline__ float exp2x(float x) {
  return __builtin_amdgcn_exp2f(x);
}
#else
__device__ __forceinline__ float exp2x(float x) {
  float r;
  asm("v_exp_f32 %0, %1\n\ts_nop 1" : "=v"(r) : "v"(x));
  return r;
}
#endif

__device__ __forceinline__ ushort f2bf(float f) {
  unsigned u = __float_as_uint(f);
  unsigned r = (u + 0x7fffu + ((u >> 16) & 1u)) >> 16;  // RNE
  return (ushort)r;
}
__device__ __forceinline__ ushort f2bf_fast(float f) {
  unsigned r;
  asm("v_cvt_pk_bf16_f32 %0, %1, %2" : "=v"(r) : "v"(f), "v"(f));
  return (ushort)r;
}
// gate scale for gate index g (0=i,1=f,2=g,3=o): sigmoid gates get -log2e
// (folds exp(-z) negation), tanh gate gets +2log2e (tanh(x)=1-2/(1+e^{2x}))
__device__ __forceinline__ float gscale(int g) {
  return (g == 2) ? 2.88539008177792681472f : -1.44269504088896340736f;
}

__global__ void prep_kernel(const float* __restrict__ w_hh0,
                            const float* __restrict__ w_ih1,
                            const float* __restrict__ w_hh1,
                            const float* __restrict__ b_ih0,
                            const float* __restrict__ b_hh0,
                            const float* __restrict__ b_ih1,
                            const float* __restrict__ b_hh1,
                            const float* __restrict__ fc_w,
                            float* __restrict__ ws) {
  const int stride = gridDim.x * blockDim.x;
  const int t0 = blockIdx.x * blockDim.x + threadIdx.x;
  ushort* bf = (ushort*)(ws + WS_BF);
  for (int i = t0; i < 96 * 512; i += stride) {
    int chunk = i >> 9, lane = (i >> 3) & 63, j = i & 7;
    float v;
    int n;
    if (chunk < 32) {
      int ks = chunk >> 4, nt = chunk & 15;
      int k = 32 * ks + 8 * (lane >> 4) + j;
      n = 16 * nt + (lane & 15);
      v = w_hh0[n * 64 + k];
    } else {
      int c2 = chunk - 32;
      int ks = c2 >> 4, nt = c2 & 15;
      int k = 32 * ks + 8 * (lane >> 4) + j;
      n = 16 * nt + (lane & 15);
      v = (k < 64) ? w_ih1[n * 64 + k] : w_hh1[n * 64 + (k - 64)];
    }
    bf[i] = f2bf(v * gscale(n >> 6));
  }
  for (int i = t0; i < 4096; i += stride) {
    int u = i >> 6, o = i & 63;
    ws[WS_FCT + i] = fc_w[o * 64 + u];
  }
  for (int i = t0; i < 256; i += stride) {
    float sc = gscale(i >> 6);
    ws[WS_B0 + i] = (b_ih0[i] + b_hh0[i]) * sc;
    ws[WS_B1 + i] = (b_ih1[i] + b_hh1[i]) * sc;
  }
  for (int i = t0; i < 32; i += stride) ws[WS_STATS + i] = 0.f;
}

// Each thread owns one chunk of 15 consecutive float4s (60 elems = 4 full
// mod-15 periods, chunk-aligned so t-indices are compile-time constants).
__global__ void bn_sums_kernel(const float* __restrict__ x,
                               float* __restrict__ ws) {
  __shared__ float ls[16], lq[16];
  const int tid = threadIdx.x;
  if (tid < 16) { ls[tid] = 0.f; lq[tid] = 0.f; }
  __syncthreads();
  const float4* x4 = (const float4*)x;
  const int c0 = (blockIdx.x * 256 + tid) * 15;
  float s[15], q[15];
#pragma unroll
  for (int t = 0; t < 15; ++t) { s[t] = 0.f; q[t] = 0.f; }
#pragma unroll
  for (int c = 0; c < 15; ++c) {
    float4 v = x4[c0 + c];
    s[(4 * c + 0) % 15] += v.x; q[(4 * c + 0) % 15] += v.x * v.x;
    s[(4 * c + 1) % 15] += v.y; q[(4 * c + 1) % 15] += v.y * v.y;
    s[(4 * c + 2) % 15] += v.z; q[(4 * c + 2) % 15] += v.z * v.z;
    s[(4 * c + 3) % 15] += v.w; q[(4 * c + 3) % 15] += v.w * v.w;
  }
#pragma unroll
  for (int t = 0; t < 15; ++t) {
    atomicAdd(&ls[t], s[t]);
    atomicAdd(&lq[t], q[t]);
  }
  __syncthreads();
  if (tid < 15) {
    atomicAdd(&ws[WS_STATS + tid], ls[tid]);
    atomicAdd(&ws[WS_STATS + 16 + tid], lq[tid]);
  }
}

__global__ void bn_final_kernel(const float* __restrict__ gamma,
                                const float* __restrict__ beta,
                                float* __restrict__ ws) {
  int t = threadIdx.x;
  if (t < 15) {
    const float inv = 1.f / (float)kB;
    float mean = ws[WS_STATS + t] * inv;
    float var = ws[WS_STATS + 16 + t] * inv - mean * mean;
    float sc = gamma[t] * rsqrtf(var + 1e-5f);
    ws[WS_SS + t] = sc;
    ws[WS_SS + 16 + t] = beta[t] - mean * sc;
  }
}

__global__ __launch_bounds__(256, 2) void lstm_fused_kernel(
    const float* __restrict__ x, const float* __restrict__ w_ih0,
    const float* __restrict__ fc_b, const float* __restrict__ ws,
    float* __restrict__ out) {
  // h0b/h1b: [parity][row][unit] ushort, XOR-swizzled rows (64-ushort rows)
  __shared__ ushort h0b[2][kM * 64];   // 16 KB
  __shared__ ushort h1b[2][kM * 64];   // 16 KB
  __shared__ float xsf[kM * 17];       // 4.3 KB
  __shared__ float h1f[kM * 68];       // 17.4 KB

  const int tid = threadIdx.x;
  const int lane = tid & 63;
  const int wv = tid >> 6;
  const int grp = lane >> 4;
  const int l15 = lane & 15;
  const int u = wv * 16 + l15;

  // ---- per-block one-time hoists ----
  float b0g[4], b1g[4], w0g[4];
#pragma unroll
  for (int j = 0; j < 4; ++j) {
    b0g[j] = ws[WS_B0 + u + 64 * j];
    b1g[j] = ws[WS_B1 + u + 64 * j];
    w0g[j] = w_ih0[u + 64 * j] * gscale(j);
  }
  const short8* bfr = (const short8*)(ws + WS_BF);
  short8 bL0[8], bL1[16];
#pragma unroll
  for (int ks = 0; ks < 2; ++ks)
#pragma unroll
    for (int j = 0; j < 4; ++j)
      bL0[ks * 4 + j] = bfr[(ks * 16 + wv + 4 * j) * 64 + lane];
#pragma unroll
  for (int ks = 0; ks < 4; ++ks)
#pragma unroll
    for (int j = 0; j < 4; ++j)
      bL1[ks * 4 + j] = bfr[(32 + ks * 16 + wv + 4 * j) * 64 + lane];

  // A-fragment read: row = l15 + 16*mt (mt 0..3), k-slice kbase+8*grp, XOR swz
  auto ldA = [&](const ushort* buf, int mt, int kbase) -> short8 {
    int row = l15 + 16 * mt;
    int off = (kbase + 8 * grp) ^ ((row & 7) << 3);
    return *(const short8*)&buf[row * 64 + off];
  };

#pragma unroll 1
  for (int tile = blockIdx.x; tile < kTiles; tile += kGrid) {
    const int bm0 = tile * kM;

    // stage x (BN folded) + zero parity-1 h buffers (t=0 reads parity 1).
    for (int i = tid; i < kM * kT; i += 256) {
      float v = x[(size_t)bm0 * kT + i];
      int m = i / 15, tt = i - m * 15;
      xsf[m * 17 + tt] = v * ws[WS_SS + tt] + ws[WS_SS + 16 + tt];
    }
    for (int i = tid; i < 2048; i += 256) {
      ((unsigned*)h0b[1])[i] = 0u;
      ((unsigned*)h1b[1])[i] = 0u;
    }

    float c0r[16], c1r[16];
#pragma unroll
    for (int i = 0; i < 16; ++i) { c0r[i] = 0.f; c1r[i] = 0.f; }

    __syncthreads();

#pragma unroll 1
    for (int t = 0; t < kT; ++t) {
      const int p = t & 1;
      const ushort* h0rd = h0b[p ^ 1];
      ushort* h0wr = h0b[p];
      const ushort* h1rd = h1b[p ^ 1];
      ushort* h1wr = h1b[p];

      // ---------------- layer 0: z0' = scaled(b0 + x*w0) + h0_{t-1} @ W ----
      f32x4 acc[4][4];
#pragma unroll
      for (int mt = 0; mt < 4; ++mt)
#pragma unroll
        for (int r = 0; r < 4; ++r) {
          float xv = xsf[(16 * mt + 4 * grp + r) * 17 + t];
#pragma unroll
          for (int j = 0; j < 4; ++j) acc[mt][j][r] = fmaf(xv, w0g[j], b0g[j]);
        }
#pragma unroll
      for (int ks = 0; ks < 2; ++ks) {
        short8 a0 = ldA(h0rd, 0, 32 * ks);
        short8 a1 = ldA(h0rd, 1, 32 * ks);
        short8 a2 = ldA(h0rd, 2, 32 * ks);
        short8 a3 = ldA(h0rd, 3, 32 * ks);
#pragma unroll
        for (int j = 0; j < 4; ++j) {
          acc[0][j] = __builtin_amdgcn_mfma_f32_16x16x32_bf16(a0, bL0[ks * 4 + j], acc[0][j], 0, 0, 0);
          acc[1][j] = __builtin_amdgcn_mfma_f32_16x16x32_bf16(a1, bL0[ks * 4 + j], acc[1][j], 0, 0, 0);
          acc[2][j] = __builtin_amdgcn_mfma_f32_16x16x32_bf16(a2, bL0[ks * 4 + j], acc[2][j], 0, 0, 0);
          acc[3][j] = __builtin_amdgcn_mfma_f32_16x16x32_bf16(a3, bL0[ks * 4 + j], acc[3][j], 0, 0, 0);
        }
      }
      // gates L0 -> h0wr (no barrier: h0wr is the parity buffer nobody reads
      // this t; L0 readers used h0rd)
#pragma unroll
      for (int mt = 0; mt < 4; ++mt)
#pragma unroll
        for (int r = 0; r < 4; ++r) {
          int row = 16 * mt + 4 * grp + r;
          float ig = __builtin_amdgcn_rcpf(1.f + exp2x(acc[mt][0][r]));
          float fg = __builtin_amdgcn_rcpf(1.f + exp2x(acc[mt][1][r]));
          float gg = 1.f - 2.f * __builtin_amdgcn_rcpf(1.f + exp2x(acc[mt][2][r]));
          float og = __builtin_amdgcn_rcpf(1.f + exp2x(acc[mt][3][r]));
          float c = fmaf(fg, c0r[mt * 4 + r], ig * gg);
          c0r[mt * 4 + r] = c;
          float th = 1.f - 2.f * __builtin_amdgcn_rcpf(1.f + exp2x(c * 2.88539008177792681472f));
          h0wr[row * 64 + (u ^ ((row & 7) << 3))] = f2bf_fast(og * th);
        }
      __syncthreads();  // the ONE barrier: h0_t visible for L1

      // ---------------- layer 1: z1' = scaled(b1) + [h0_t; h1_{t-1}] @ W ----
#pragma unroll
      for (int mt = 0; mt < 4; ++mt)
#pragma unroll
        for (int j = 0; j < 4; ++j)
#pragma unroll
          for (int r = 0; r < 4; ++r) acc[mt][j][r] = b1g[j];
#pragma unroll
      for (int ks = 0; ks < 2; ++ks) {
        short8 a0 = ldA(h0wr, 0, 32 * ks);
        short8 a1 = ldA(h0wr, 1, 32 * ks);
        short8 a2 = ldA(h0wr, 2, 32 * ks);
        short8 a3 = ldA(h0wr, 3, 32 * ks);
#pragma unroll
        for (int j = 0; j < 4; ++j) {
          acc[0][j] = __builtin_amdgcn_mfma_f32_16x16x32_bf16(a0, bL1[ks * 4 + j], acc[0][j], 0, 0, 0);
          acc[1][j] = __builtin_amdgcn_mfma_f32_16x16x32_bf16(a1, bL1[ks * 4 + j], acc[1][j], 0, 0, 0);
          acc[2][j] = __builtin_amdgcn_mfma_f32_16x16x32_bf16(a2, bL1[ks * 4 + j], acc[2][j], 0, 0, 0);
          acc[3][j] = __builtin_amdgcn_mfma_f32_16x16x32_bf16(a3, bL1[ks * 4 + j], acc[3][j], 0, 0, 0);
        }
      }
#pragma unroll
      for (int ks = 2; ks < 4; ++ks) {
        short8 a0 = ldA(h1rd, 0, 32 * (ks - 2));
        short8 a1 = ldA(h1rd, 1, 32 * (ks - 2));
        short8 a2 = ldA(h1rd, 2, 32 * (ks - 2));
        short8 a3 = ldA(h1rd, 3, 32 * (ks - 2));
#pragma unroll
        for (int j = 0; j < 4; ++j) {
          acc[0][j] = __builtin_amdgcn_mfma_f32_16x16x32_bf16(a0, bL1[ks * 4 + j], acc[0][j], 0, 0, 0);
          acc[1][j] = __builtin_amdgcn_mfma_f32_16x16x32_bf16(a1, bL1[ks * 4 + j], acc[1][j], 0, 0, 0);
          acc[2][j] = __builtin_amdgcn_mfma_f32_16x16x32_bf16(a2, bL1[ks * 4 + j], acc[2][j], 0, 0, 0);
          acc[3][j] = __builtin_amdgcn_mfma_f32_16x16x32_bf16(a3, bL1[ks * 4 + j], acc[3][j], 0, 0, 0);
        }
      }
      // gates L1 -> h1wr (no barrier: h1wr is the unread parity buffer)
#pragma unroll
      for (int mt = 0; mt < 4; ++mt)
#pragma unroll
        for (int r = 0; r < 4; ++r) {
          int row = 16 * mt + 4 * grp + r;
          float ig = __builtin_amdgcn_rcpf(1.f + exp2x(acc[mt][0][r]));
          float fg = __builtin_amdgcn_rcpf(1.f + exp2x(acc[mt][1][r]));
          float gg = 1.f - 2.f * __builtin_amdgcn_rcpf(1.f + exp2x(acc[mt][2][r]));
          float og = __builtin_amdgcn_rcpf(1.f + exp2x(acc[mt][3][r]));
          float c = fmaf(fg, c1r[mt * 4 + r], ig * gg);
          c1r[mt * 4 + r] = c;
          float th = 1.f - 2.f * __builtin_amdgcn_rcpf(1.f + exp2x(c * 2.88539008177792681472f));
          float h = og * th;
          if (t < kT - 1) {
            h1wr[row * 64 + (u ^ ((row & 7) << 3))] = f2bf_fast(h);
          } else {
            h1f[row * 68 + u] = h;
          }
        }
    }
    __syncthreads();  // h1f visible for FC (also drains last L1-mfma reads)

    // ---------------- FC + exact-erf GELU (fp32) ----------------
    {
      const int o = tid & 63;
      const int ms = tid >> 6;  // rows ms*16 .. ms*16+15
      float yv[16];
      float fb = fc_b[o];
#pragma unroll
      for (int i = 0; i < 16; ++i) yv[i] = fb;
#pragma unroll 1
      for (int u0 = 0; u0 < 64; u0 += 4) {
        float q0 = ws[WS_FCT + (u0 + 0) * 64 + o];
        float q1 = ws[WS_FCT + (u0 + 1) * 64 + o];
        float q2 = ws[WS_FCT + (u0 + 2) * 64 + o];
        float q3 = ws[WS_FCT + (u0 + 3) * 64 + o];
#pragma unroll
        for (int i = 0; i < 16; ++i) {
          const float4 hq = *(const float4*)&h1f[(ms * 16 + i) * 68 + u0];
          yv[i] = fmaf(hq.x, q0, yv[i]);
          yv[i] = fmaf(hq.y, q1, yv[i]);
          yv[i] = fmaf(hq.z, q2, yv[i]);
          yv[i] = fmaf(hq.w, q3, yv[i]);
        }
      }
#pragma unroll
      for (int i = 0; i < 16; ++i) {
        float v = yv[i];
        float g = 0.5f * v * (1.f + erff(v * 0.70710678118654752f));
        out[(size_t)(bm0 + ms * 16 + i) * 64 + o] = g;
      }
    }
    // no barrier: next tile's staging (h0b[1]/h1b[1]/xsf) is disjoint from
    // h1f/out, and all h-buffer reads ended before the post-loop barrier.
  }
}

extern "C" void kernel_launch(void* const* d_in, const int* in_sizes, int n_in,
                              void* d_out, int out_size, void* d_ws, size_t ws_size,
                              hipStream_t stream) {
  const float* x = (const float*)d_in[0];
  const float* bn_gamma = (const float*)d_in[1];
  const float* bn_beta = (const float*)d_in[2];
  const float* w_ih0 = (const float*)d_in[3];
  const float* w_hh0 = (const float*)d_in[4];
  const float* b_ih0 = (const float*)d_in[5];
  const float* b_hh0 = (const float*)d_in[6];
  const float* w_ih1 = (const float*)d_in[7];
  const float* w_hh1 = (const float*)d_in[8];
  const float* b_ih1 = (const float*)d_in[9];
  const float* b_hh1 = (const float*)d_in[10];
  const float* fc_w = (const float*)d_in[11];
  const float* fc_b = (const float*)d_in[12];
  float* ws = (float*)d_ws;
  float* out = (float*)d_out;

  hipLaunchKernelGGL(prep_kernel, dim3(64), dim3(256), 0, stream,
                     w_hh0, w_ih1, w_hh1, b_ih0, b_hh0, b_ih1, b_hh1, fc_w, ws);
  hipLaunchKernelGGL(bn_sums_kernel, dim3(256), dim3(256), 0, stream, x, ws);
  hipLaunchKernelGGL(bn_final_kernel, dim3(1), dim3(64), 0, stream,
                     bn_gamma, bn_beta, ws);
  hipLaunchKernelGGL(lstm_fused_kernel, dim3(kGrid), dim3(256), 0, stream,
                     x, w_ih0, fc_b, ws, out);
}

// Round 13
// 1183.695 us; speedup vs baseline: 1.3103x; 1.3103x over previous
//
#include <hip/hip_runtime.h>
#include <math.h>

// BN(ch=T) -> LSTM(1->64) -> LSTM(64->64) -> FC+GELU.  B=262144 T=15 H=64.
// v13: v11 (M=32, grid 512, (256,2), 1-barrier/t parity buffers, exp2-domain
//      gates) + in-wave software pipeline: L0-MFMA(t+1) is issued right after
//      L1-MFMA(t) (both read the barrier-ordered h0b[p]), so gates1(t) hides
//      L0(t+1)'s latency and gates0(t+1) hides L1's. One barrier per t, now
//      at the end of the iteration. v12 lesson: +94 regs demotes; this +32.
//
// ws float offsets:
//   WS_SS    0     scale[15]@+0, shift[15]@+16
//   WS_B0    32    scaled b_ih0+b_hh0 [256]
//   WS_B1    288   scaled b_ih1+b_hh1 [256]
//   WS_FCT   1024  fcT[u][o] fp32 [64][64]  (unscaled)
//   WS_STATS 5200  bn sums[15]@+0, sqsums[15]@+16
//   WS_BF    8192  bf16 B-fragments (gate-scaled): 96 chunks x 512 ushort
//     chunk<32:  L0 (w_hh0^T):  ks=chunk>>4 (K=64: 2), nt=chunk&15
//     chunk>=32: L1 ([w_ih1;w_hh1]^T): ks=(chunk-32)>>4 (K=128: 4), nt=&15
//     elem(lane,j) = B[k=32*ks+8*(lane>>4)+j][n=16*nt+(lane&15)]

typedef __attribute__((ext_vector_type(8))) short short8;
typedef __attribute__((ext_vector_type(4))) float f32x4;

namespace {
constexpr int kB = 262144;
constexpr int kT = 15;
constexpr int kTiles = kB / 32;   // 8192
constexpr int kGrid = 512;        // 2 blocks per CU; 16 tiles per block
constexpr int WS_SS = 0;
constexpr int WS_B0 = 32;
constexpr int WS_B1 = 288;
constexpr int WS_FCT = 1024;
constexpr int WS_STATS = 5200;
constexpr int WS_BF = 8192;
}  // namespace

#if __has_builtin(__builtin_amdgcn_exp2f)
__device__ __forceinline__ float exp2x(float x) {
  return __builtin_amdgcn_exp2f(x);
}
#else
__device__ __forceinline__ float exp2x(float x) {
  float r;
  asm("v_exp_f32 %0, %1\n\ts_nop 1" : "=v"(r) : "v"(x));
  return r;
}
#endif

__device__ __forceinline__ ushort f2bf(float f) {
  unsigned u = __float_as_uint(f);
  unsigned r = (u + 0x7fffu + ((u >> 16) & 1u)) >> 16;  // RNE
  return (ushort)r;
}
__device__ __forceinline__ ushort f2bf_fast(float f) {
  unsigned r;
  asm("v_cvt_pk_bf16_f32 %0, %1, %2" : "=v"(r) : "v"(f), "v"(f));
  return (ushort)r;
}
// gate scale for gate index g (0=i,1=f,2=g,3=o): sigmoid gates get -log2e
// (folds exp(-z) negation), tanh gate gets +2log2e (tanh(x)=1-2/(1+e^{2x}))
__device__ __forceinline__ float gscale(int g) {
  return (g == 2) ? 2.88539008177792681472f : -1.44269504088896340736f;
}

__global__ void prep_kernel(const float* __restrict__ w_hh0,
                            const float* __restrict__ w_ih1,
                            const float* __restrict__ w_hh1,
                            const float* __restrict__ b_ih0,
                            const float* __restrict__ b_hh0,
                            const float* __restrict__ b_ih1,
                            const float* __restrict__ b_hh1,
                            const float* __restrict__ fc_w,
                            float* __restrict__ ws) {
  const int stride = gridDim.x * blockDim.x;
  const int t0 = blockIdx.x * blockDim.x + threadIdx.x;
  ushort* bf = (ushort*)(ws + WS_BF);
  for (int i = t0; i < 96 * 512; i += stride) {
    int chunk = i >> 9, lane = (i >> 3) & 63, j = i & 7;
    float v;
    int n;
    if (chunk < 32) {
      int ks = chunk >> 4, nt = chunk & 15;
      int k = 32 * ks + 8 * (lane >> 4) + j;
      n = 16 * nt + (lane & 15);
      v = w_hh0[n * 64 + k];
    } else {
      int c2 = chunk - 32;
      int ks = c2 >> 4, nt = c2 & 15;
      int k = 32 * ks + 8 * (lane >> 4) + j;
      n = 16 * nt + (lane & 15);
      v = (k < 64) ? w_ih1[n * 64 + k] : w_hh1[n * 64 + (k - 64)];
    }
    bf[i] = f2bf(v * gscale(n >> 6));
  }
  for (int i = t0; i < 4096; i += stride) {
    int u = i >> 6, o = i & 63;
    ws[WS_FCT + i] = fc_w[o * 64 + u];
  }
  for (int i = t0; i < 256; i += stride) {
    float sc = gscale(i >> 6);
    ws[WS_B0 + i] = (b_ih0[i] + b_hh0[i]) * sc;
    ws[WS_B1 + i] = (b_ih1[i] + b_hh1[i]) * sc;
  }
  for (int i = t0; i < 32; i += stride) ws[WS_STATS + i] = 0.f;
}

// Each thread owns one chunk of 15 consecutive float4s (60 elems = 4 full
// mod-15 periods, chunk-aligned so t-indices are compile-time constants).
__global__ void bn_sums_kernel(const float* __restrict__ x,
                               float* __restrict__ ws) {
  __shared__ float ls[16], lq[16];
  const int tid = threadIdx.x;
  if (tid < 16) { ls[tid] = 0.f; lq[tid] = 0.f; }
  __syncthreads();
  const float4* x4 = (const float4*)x;
  const int c0 = (blockIdx.x * 256 + tid) * 15;
  float s[15], q[15];
#pragma unroll
  for (int t = 0; t < 15; ++t) { s[t] = 0.f; q[t] = 0.f; }
#pragma unroll
  for (int c = 0; c < 15; ++c) {
    float4 v = x4[c0 + c];
    s[(4 * c + 0) % 15] += v.x; q[(4 * c + 0) % 15] += v.x * v.x;
    s[(4 * c + 1) % 15] += v.y; q[(4 * c + 1) % 15] += v.y * v.y;
    s[(4 * c + 2) % 15] += v.z; q[(4 * c + 2) % 15] += v.z * v.z;
    s[(4 * c + 3) % 15] += v.w; q[(4 * c + 3) % 15] += v.w * v.w;
  }
#pragma unroll
  for (int t = 0; t < 15; ++t) {
    atomicAdd(&ls[t], s[t]);
    atomicAdd(&lq[t], q[t]);
  }
  __syncthreads();
  if (tid < 15) {
    atomicAdd(&ws[WS_STATS + tid], ls[tid]);
    atomicAdd(&ws[WS_STATS + 16 + tid], lq[tid]);
  }
}

__global__ void bn_final_kernel(const float* __restrict__ gamma,
                                const float* __restrict__ beta,
                                float* __restrict__ ws) {
  int t = threadIdx.x;
  if (t < 15) {
    const float inv = 1.f / (float)kB;
    float mean = ws[WS_STATS + t] * inv;
    float var = ws[WS_STATS + 16 + t] * inv - mean * mean;
    float sc = gamma[t] * rsqrtf(var + 1e-5f);
    ws[WS_SS + t] = sc;
    ws[WS_SS + 16 + t] = beta[t] - mean * sc;
  }
}

__global__ __launch_bounds__(256, 2) void lstm_fused_kernel(
    const float* __restrict__ x, const float* __restrict__ w_ih0,
    const float* __restrict__ fc_b, const float* __restrict__ ws,
    float* __restrict__ out) {
  // h0b/h1b: [parity][row][unit] ushort, XOR-swizzled rows (64-ushort rows)
  __shared__ ushort h0b[2][32 * 64];   // 8 KB
  __shared__ ushort h1b[2][32 * 64];   // 8 KB
  __shared__ float xsf[32 * 17];       // 2.2 KB
  __shared__ float h1f[32 * 68];       // 8.7 KB

  const int tid = threadIdx.x;
  const int lane = tid & 63;
  const int wv = tid >> 6;
  const int grp = lane >> 4;
  const int l15 = lane & 15;
  const int u = wv * 16 + l15;

  // ---- per-block one-time hoists ----
  float b0g[4], b1g[4], w0g[4];
#pragma unroll
  for (int j = 0; j < 4; ++j) {
    b0g[j] = ws[WS_B0 + u + 64 * j];
    b1g[j] = ws[WS_B1 + u + 64 * j];
    w0g[j] = w_ih0[u + 64 * j] * gscale(j);
  }
  const short8* bfr = (const short8*)(ws + WS_BF);
  short8 bL0[8], bL1[16];
#pragma unroll
  for (int ks = 0; ks < 2; ++ks)
#pragma unroll
    for (int j = 0; j < 4; ++j)
      bL0[ks * 4 + j] = bfr[(ks * 16 + wv + 4 * j) * 64 + lane];
#pragma unroll
  for (int ks = 0; ks < 4; ++ks)
#pragma unroll
    for (int j = 0; j < 4; ++j)
      bL1[ks * 4 + j] = bfr[(32 + ks * 16 + wv + 4 * j) * 64 + lane];

  // A-fragment read: rows 0..15 (+16*mt), k-slice base kbase+8*grp, XOR swz
  auto ldA = [&](const ushort* buf, int mt, int kbase) -> short8 {
    int row = l15 + 16 * mt;
    int off = (kbase + 8 * grp) ^ ((row & 7) << 3);
    return *(const short8*)&buf[row * 64 + off];
  };

  f32x4 accL0[2][4], accL1[2][4];

  // x-init + L0 MFMA for timestep tt, reading h-state from h0src
  auto doL0 = [&](int tt, const ushort* h0src) {
#pragma unroll
    for (int mt = 0; mt < 2; ++mt)
#pragma unroll
      for (int r = 0; r < 4; ++r) {
        float xv = xsf[(16 * mt + 4 * grp + r) * 17 + tt];
#pragma unroll
        for (int j = 0; j < 4; ++j) accL0[mt][j][r] = fmaf(xv, w0g[j], b0g[j]);
      }
#pragma unroll
    for (int ks = 0; ks < 2; ++ks) {
      short8 a0 = ldA(h0src, 0, 32 * ks);
      short8 a1 = ldA(h0src, 1, 32 * ks);
#pragma unroll
      for (int j = 0; j < 4; ++j) {
        accL0[0][j] = __builtin_amdgcn_mfma_f32_16x16x32_bf16(a0, bL0[ks * 4 + j], accL0[0][j], 0, 0, 0);
        accL0[1][j] = __builtin_amdgcn_mfma_f32_16x16x32_bf16(a1, bL0[ks * 4 + j], accL0[1][j], 0, 0, 0);
      }
    }
  };

  // gates on acc -> h (bf16 swizzled store into dst), c-state in cr[8]
  auto doGates = [&](f32x4 (&acc)[2][4], float* cr, ushort* dst) {
#pragma unroll
    for (int mt = 0; mt < 2; ++mt)
#pragma unroll
      for (int r = 0; r < 4; ++r) {
        int row = 16 * mt + 4 * grp + r;
        float ig = __builtin_amdgcn_rcpf(1.f + exp2x(acc[mt][0][r]));
        float fg = __builtin_amdgcn_rcpf(1.f + exp2x(acc[mt][1][r]));
        float gg = 1.f - 2.f * __builtin_amdgcn_rcpf(1.f + exp2x(acc[mt][2][r]));
        float og = __builtin_amdgcn_rcpf(1.f + exp2x(acc[mt][3][r]));
        float c = fmaf(fg, cr[mt * 4 + r], ig * gg);
        cr[mt * 4 + r] = c;
        float th = 1.f - 2.f * __builtin_amdgcn_rcpf(1.f + exp2x(c * 2.88539008177792681472f));
        dst[row * 64 + (u ^ ((row & 7) << 3))] = f2bf_fast(og * th);
      }
  };

#pragma unroll 1
  for (int tile = blockIdx.x; tile < kTiles; tile += kGrid) {
    const int bm0 = tile * 32;

    // stage x (BN folded) + zero parity-1 h buffers (t=0 reads parity 1).
    for (int i = tid; i < 32 * kT; i += 256) {
      float v = x[(size_t)bm0 * kT + i];
      int m = i / 15, tt = i - m * 15;
      xsf[m * 17 + tt] = v * ws[WS_SS + tt] + ws[WS_SS + 16 + tt];
    }
    for (int i = tid; i < 1024; i += 256) {
      ((unsigned*)h0b[1])[i] = 0u;
      ((unsigned*)h1b[1])[i] = 0u;
    }

    float c0r[8], c1r[8];
#pragma unroll
    for (int i = 0; i < 8; ++i) { c0r[i] = 0.f; c1r[i] = 0.f; }

    __syncthreads();

    // ---- prologue: L0(0) + gates0(0) -> h0b[0] ----
    doL0(0, h0b[1]);
    doGates(accL0, c0r, h0b[0]);
    __syncthreads();  // h0_0 visible

#pragma unroll 1
    for (int t = 0; t < kT; ++t) {
      const int p = t & 1;

      // ---- L1 MFMA(t): reads h0b[p] (ks0-1) + h1b[p^1] (ks2-3) ----
#pragma unroll
      for (int mt = 0; mt < 2; ++mt)
#pragma unroll
        for (int j = 0; j < 4; ++j)
#pragma unroll
          for (int r = 0; r < 4; ++r) accL1[mt][j][r] = b1g[j];
#pragma unroll
      for (int ks = 0; ks < 2; ++ks) {
        short8 a0 = ldA(h0b[p], 0, 32 * ks);
        short8 a1 = ldA(h0b[p], 1, 32 * ks);
#pragma unroll
        for (int j = 0; j < 4; ++j) {
          accL1[0][j] = __builtin_amdgcn_mfma_f32_16x16x32_bf16(a0, bL1[ks * 4 + j], accL1[0][j], 0, 0, 0);
          accL1[1][j] = __builtin_amdgcn_mfma_f32_16x16x32_bf16(a1, bL1[ks * 4 + j], accL1[1][j], 0, 0, 0);
        }
      }
#pragma unroll
      for (int ks = 2; ks < 4; ++ks) {
        short8 a0 = ldA(h1b[p ^ 1], 0, 32 * (ks - 2));
        short8 a1 = ldA(h1b[p ^ 1], 1, 32 * (ks - 2));
#pragma unroll
        for (int j = 0; j < 4; ++j) {
          accL1[0][j] = __builtin_amdgcn_mfma_f32_16x16x32_bf16(a0, bL1[ks * 4 + j], accL1[0][j], 0, 0, 0);
          accL1[1][j] = __builtin_amdgcn_mfma_f32_16x16x32_bf16(a1, bL1[ks * 4 + j], accL1[1][j], 0, 0, 0);
        }
      }

      // ---- hoisted L0 MFMA(t+1): reads h0b[p] (== h0rd of t+1) ----
      if (t < kT - 1) doL0(t + 1, h0b[p]);

      // ---- gates1(t): L1 latency was covered by the L0(t+1) issue ----
      if (t < kT - 1) {
        doGates(accL1, c1r, h1b[p]);
      } else {
#pragma unroll
        for (int mt = 0; mt < 2; ++mt)
#pragma unroll
          for (int r = 0; r < 4; ++r) {
            int row = 16 * mt + 4 * grp + r;
            float ig = __builtin_amdgcn_rcpf(1.f + exp2x(accL1[mt][0][r]));
            float fg = __builtin_amdgcn_rcpf(1.f + exp2x(accL1[mt][1][r]));
            float gg = 1.f - 2.f * __builtin_amdgcn_rcpf(1.f + exp2x(accL1[mt][2][r]));
            float og = __builtin_amdgcn_rcpf(1.f + exp2x(accL1[mt][3][r]));
            float c = fmaf(fg, c1r[mt * 4 + r], ig * gg);
            c1r[mt * 4 + r] = c;
            float th = 1.f - 2.f * __builtin_amdgcn_rcpf(1.f + exp2x(c * 2.88539008177792681472f));
            h1f[row * 68 + u] = og * th;
          }
      }

      // ---- gates0(t+1): L0 latency covered by gates1's VALU ----
      if (t < kT - 1) {
        doGates(accL0, c0r, h0b[p ^ 1]);
        __syncthreads();  // the ONE barrier: h0_{t+1} + h1_t visible
      }
    }
    __syncthreads();  // h1f visible for FC (drains last L1-mfma reads)

    // ---------------- FC + exact-erf GELU (fp32) ----------------
    {
      const int o = tid & 63;
      const int ms = tid >> 6;
      float yv[8];
      float fb = fc_b[o];
#pragma unroll
      for (int i = 0; i < 8; ++i) yv[i] = fb;
#pragma unroll 1
      for (int u0 = 0; u0 < 64; u0 += 4) {
        float q0 = ws[WS_FCT + (u0 + 0) * 64 + o];
        float q1 = ws[WS_FCT + (u0 + 1) * 64 + o];
        float q2 = ws[WS_FCT + (u0 + 2) * 64 + o];
        float q3 = ws[WS_FCT + (u0 + 3) * 64 + o];
#pragma unroll
        for (int i = 0; i < 8; ++i) {
          const float4 hq = *(const float4*)&h1f[(ms * 8 + i) * 68 + u0];
          yv[i] = fmaf(hq.x, q0, yv[i]);
          yv[i] = fmaf(hq.y, q1, yv[i]);
          yv[i] = fmaf(hq.z, q2, yv[i]);
          yv[i] = fmaf(hq.w, q3, yv[i]);
        }
      }
#pragma unroll
      for (int i = 0; i < 8; ++i) {
        float v = yv[i];
        float g = 0.5f * v * (1.f + erff(v * 0.70710678118654752f));
        out[(size_t)(bm0 + ms * 8 + i) * 64 + o] = g;
      }
    }
    // no barrier: next tile's staging (h0b[1]/h1b[1]/xsf) was last read
    // before the post-loop barrier; h1f/out are disjoint from staging.
  }
}

extern "C" void kernel_launch(void* const* d_in, const int* in_sizes, int n_in,
                              void* d_out, int out_size, void* d_ws, size_t ws_size,
                              hipStream_t stream) {
  const float* x = (const float*)d_in[0];
  const float* bn_gamma = (const float*)d_in[1];
  const float* bn_beta = (const float*)d_in[2];
  const float* w_ih0 = (const float*)d_in[3];
  const float* w_hh0 = (const float*)d_in[4];
  const float* b_ih0 = (const float*)d_in[5];
  const float* b_hh0 = (const float*)d_in[6];
  const float* w_ih1 = (const float*)d_in[7];
  const float* w_hh1 = (const float*)d_in[8];
  const float* b_ih1 = (const float*)d_in[9];
  const float* b_hh1 = (const float*)d_in[10];
  const float* fc_w = (const float*)d_in[11];
  const float* fc_b = (const float*)d_in[12];
  float* ws = (float*)d_ws;
  float* out = (float*)d_out;

  hipLaunchKernelGGL(prep_kernel, dim3(64), dim3(256), 0, stream,
                     w_hh0, w_ih1, w_hh1, b_ih0, b_hh0, b_ih1, b_hh1, fc_w, ws);
  hipLaunchKernelGGL(bn_sums_kernel, dim3(256), dim3(256), 0, stream, x, ws);
  hipLaunchKernelGGL(bn_final_kernel, dim3(1), dim3(64), 0, stream,
                     bn_gamma, bn_beta, ws);
  hipLaunchKernelGGL(lstm_fused_kernel, dim3(kGrid), dim3(256), 0, stream,
                     x, w_ih0, fc_b, ws, out);
}

// Round 14
// 776.236 us; speedup vs baseline: 1.9981x; 1.5249x over previous
//
#include <hip/hip_runtime.h>
#include <math.h>

// BN(ch=T) -> LSTM(1->64) -> LSTM(64->64) -> FC+GELU.  B=262144 T=15 H=64.
// v14: v11 (best, 814us) + packed-f32 gate math: gate arithmetic done on
//      f32x2 row-pairs so LLVM emits v_pk_{add,mul,fma}_f32 (VOP3P, 2 f32 /
//      issue slot) and v_cvt_pk_bf16_f32 converts TWO h values per instr.
//      Trans ops (exp2/rcp) stay scalar (no packed transcendentals).
//      v13 lesson: hand software-pipelining regressed (compiler's schedule
//      was better); this cuts issue slots without touching the schedule.
//
// ws float offsets:
//   WS_SS    0     scale[15]@+0, shift[15]@+16
//   WS_B0    32    scaled b_ih0+b_hh0 [256]
//   WS_B1    288   scaled b_ih1+b_hh1 [256]
//   WS_FCT   1024  fcT[u][o] fp32 [64][64]  (unscaled)
//   WS_STATS 5200  bn sums[15]@+0, sqsums[15]@+16
//   WS_BF    8192  bf16 B-fragments (gate-scaled): 96 chunks x 512 ushort
//     chunk<32:  L0 (w_hh0^T):  ks=chunk>>4 (K=64: 2), nt=chunk&15
//     chunk>=32: L1 ([w_ih1;w_hh1]^T): ks=(chunk-32)>>4 (K=128: 4), nt=&15
//     elem(lane,j) = B[k=32*ks+8*(lane>>4)+j][n=16*nt+(lane&15)]

typedef __attribute__((ext_vector_type(8))) short short8;
typedef __attribute__((ext_vector_type(4))) float f32x4;
typedef __attribute__((ext_vector_type(2))) float f32x2;

namespace {
constexpr int kB = 262144;
constexpr int kT = 15;
constexpr int kTiles = kB / 32;   // 8192
constexpr int kGrid = 512;        // 2 blocks per CU; 16 tiles per block
constexpr int WS_SS = 0;
constexpr int WS_B0 = 32;
constexpr int WS_B1 = 288;
constexpr int WS_FCT = 1024;
constexpr int WS_STATS = 5200;
constexpr int WS_BF = 8192;
}  // namespace

#if __has_builtin(__builtin_amdgcn_exp2f)
__device__ __forceinline__ float exp2x(float x) {
  return __builtin_amdgcn_exp2f(x);
}
#else
__device__ __forceinline__ float exp2x(float x) {
  float r;
  asm("v_exp_f32 %0, %1\n\ts_nop 1" : "=v"(r) : "v"(x));
  return r;
}
#endif

__device__ __forceinline__ ushort f2bf(float f) {
  unsigned u = __float_as_uint(f);
  unsigned r = (u + 0x7fffu + ((u >> 16) & 1u)) >> 16;  // RNE
  return (ushort)r;
}
// pack two f32 -> two bf16 in one u32 (RNE), single HW instr
__device__ __forceinline__ unsigned cvtpk2(float lo, float hi) {
  unsigned r;
  asm("v_cvt_pk_bf16_f32 %0, %1, %2" : "=v"(r) : "v"(lo), "v"(hi));
  return r;
}
// 1/(1+2^z) elementwise on a pair; exp2/rcp scalar, add packed
__device__ __forceinline__ f32x2 rcp1pex(f32x2 z) {
  f32x2 e;
  e.x = exp2x(z.x);
  e.y = exp2x(z.y);
  f32x2 d = e + 1.f;           // v_pk_add_f32
  f32x2 r;
  r.x = __builtin_amdgcn_rcpf(d.x);
  r.y = __builtin_amdgcn_rcpf(d.y);
  return r;
}
// gate scale for gate index g (0=i,1=f,2=g,3=o): sigmoid gates get -log2e
// (folds exp(-z) negation), tanh gate gets +2log2e (tanh(x)=1-2/(1+e^{2x}))
__device__ __forceinline__ float gscale(int g) {
  return (g == 2) ? 2.88539008177792681472f : -1.44269504088896340736f;
}

__global__ void prep_kernel(const float* __restrict__ w_hh0,
                            const float* __restrict__ w_ih1,
                            const float* __restrict__ w_hh1,
                            const float* __restrict__ b_ih0,
                            const float* __restrict__ b_hh0,
                            const float* __restrict__ b_ih1,
                            const float* __restrict__ b_hh1,
                            const float* __restrict__ fc_w,
                            float* __restrict__ ws) {
  const int stride = gridDim.x * blockDim.x;
  const int t0 = blockIdx.x * blockDim.x + threadIdx.x;
  ushort* bf = (ushort*)(ws + WS_BF);
  for (int i = t0; i < 96 * 512; i += stride) {
    int chunk = i >> 9, lane = (i >> 3) & 63, j = i & 7;
    float v;
    int n;
    if (chunk < 32) {
      int ks = chunk >> 4, nt = chunk & 15;
      int k = 32 * ks + 8 * (lane >> 4) + j;
      n = 16 * nt + (lane & 15);
      v = w_hh0[n * 64 + k];
    } else {
      int c2 = chunk - 32;
      int ks = c2 >> 4, nt = c2 & 15;
      int k = 32 * ks + 8 * (lane >> 4) + j;
      n = 16 * nt + (lane & 15);
      v = (k < 64) ? w_ih1[n * 64 + k] : w_hh1[n * 64 + (k - 64)];
    }
    bf[i] = f2bf(v * gscale(n >> 6));
  }
  for (int i = t0; i < 4096; i += stride) {
    int u = i >> 6, o = i & 63;
    ws[WS_FCT + i] = fc_w[o * 64 + u];
  }
  for (int i = t0; i < 256; i += stride) {
    float sc = gscale(i >> 6);
    ws[WS_B0 + i] = (b_ih0[i] + b_hh0[i]) * sc;
    ws[WS_B1 + i] = (b_ih1[i] + b_hh1[i]) * sc;
  }
  for (int i = t0; i < 32; i += stride) ws[WS_STATS + i] = 0.f;
}

// Each thread owns one chunk of 15 consecutive float4s (60 elems = 4 full
// mod-15 periods, chunk-aligned so t-indices are compile-time constants).
__global__ void bn_sums_kernel(const float* __restrict__ x,
                               float* __restrict__ ws) {
  __shared__ float ls[16], lq[16];
  const int tid = threadIdx.x;
  if (tid < 16) { ls[tid] = 0.f; lq[tid] = 0.f; }
  __syncthreads();
  const float4* x4 = (const float4*)x;
  const int c0 = (blockIdx.x * 256 + tid) * 15;
  float s[15], q[15];
#pragma unroll
  for (int t = 0; t < 15; ++t) { s[t] = 0.f; q[t] = 0.f; }
#pragma unroll
  for (int c = 0; c < 15; ++c) {
    float4 v = x4[c0 + c];
    s[(4 * c + 0) % 15] += v.x; q[(4 * c + 0) % 15] += v.x * v.x;
    s[(4 * c + 1) % 15] += v.y; q[(4 * c + 1) % 15] += v.y * v.y;
    s[(4 * c + 2) % 15] += v.z; q[(4 * c + 2) % 15] += v.z * v.z;
    s[(4 * c + 3) % 15] += v.w; q[(4 * c + 3) % 15] += v.w * v.w;
  }
#pragma unroll
  for (int t = 0; t < 15; ++t) {
    atomicAdd(&ls[t], s[t]);
    atomicAdd(&lq[t], q[t]);
  }
  __syncthreads();
  if (tid < 15) {
    atomicAdd(&ws[WS_STATS + tid], ls[tid]);
    atomicAdd(&ws[WS_STATS + 16 + tid], lq[tid]);
  }
}

__global__ void bn_final_kernel(const float* __restrict__ gamma,
                                const float* __restrict__ beta,
                                float* __restrict__ ws) {
  int t = threadIdx.x;
  if (t < 15) {
    const float inv = 1.f / (float)kB;
    float mean = ws[WS_STATS + t] * inv;
    float var = ws[WS_STATS + 16 + t] * inv - mean * mean;
    float sc = gamma[t] * rsqrtf(var + 1e-5f);
    ws[WS_SS + t] = sc;
    ws[WS_SS + 16 + t] = beta[t] - mean * sc;
  }
}

__global__ __launch_bounds__(256, 2) void lstm_fused_kernel(
    const float* __restrict__ x, const float* __restrict__ w_ih0,
    const float* __restrict__ fc_b, const float* __restrict__ ws,
    float* __restrict__ out) {
  // h0b/h1b: [parity][row][unit] ushort, XOR-swizzled rows (64-ushort rows)
  __shared__ ushort h0b[2][32 * 64];   // 8 KB
  __shared__ ushort h1b[2][32 * 64];   // 8 KB
  __shared__ float xsf[32 * 17];       // 2.2 KB
  __shared__ float h1f[32 * 68];       // 8.7 KB

  const int tid = threadIdx.x;
  const int lane = tid & 63;
  const int wv = tid >> 6;
  const int grp = lane >> 4;
  const int l15 = lane & 15;
  const int u = wv * 16 + l15;

  // ---- per-block one-time hoists ----
  float b0g[4], b1g[4], w0g[4];
#pragma unroll
  for (int j = 0; j < 4; ++j) {
    b0g[j] = ws[WS_B0 + u + 64 * j];
    b1g[j] = ws[WS_B1 + u + 64 * j];
    w0g[j] = w_ih0[u + 64 * j] * gscale(j);
  }
  const short8* bfr = (const short8*)(ws + WS_BF);
  short8 bL0[8], bL1[16];
#pragma unroll
  for (int ks = 0; ks < 2; ++ks)
#pragma unroll
    for (int j = 0; j < 4; ++j)
      bL0[ks * 4 + j] = bfr[(ks * 16 + wv + 4 * j) * 64 + lane];
#pragma unroll
  for (int ks = 0; ks < 4; ++ks)
#pragma unroll
    for (int j = 0; j < 4; ++j)
      bL1[ks * 4 + j] = bfr[(32 + ks * 16 + wv + 4 * j) * 64 + lane];

  // A-fragment read: rows 0..15 (+16*mt), k-slice base kbase+8*grp, XOR swz
  auto ldA = [&](const ushort* buf, int mt, int kbase) -> short8 {
    int row = l15 + 16 * mt;
    int off = (kbase + 8 * grp) ^ ((row & 7) << 3);
    return *(const short8*)&buf[row * 64 + off];
  };

  // packed gates on one row-pair: returns h pair, updates c pair.
  // zi/zf/zg/zo are pre-scaled (exp2 domain).
  auto gatesPK = [&](f32x2 zi, f32x2 zf, f32x2 zg, f32x2 zo,
                     f32x2& cp) -> f32x2 {
    f32x2 ig = rcp1pex(zi);
    f32x2 fg = rcp1pex(zf);
    f32x2 rg = rcp1pex(zg);
    f32x2 gg = 1.f - 2.f * rg;          // v_pk_fma
    f32x2 og = rcp1pex(zo);
    f32x2 c = fg * cp + ig * gg;        // pk_mul + pk_fma + pk_mul
    cp = c;
    f32x2 rt = rcp1pex(c * 2.88539008177792681472f);  // pk_mul inside
    f32x2 th = 1.f - 2.f * rt;          // pk_fma
    return og * th;                     // pk_mul
  };

#pragma unroll 1
  for (int tile = blockIdx.x; tile < kTiles; tile += kGrid) {
    const int bm0 = tile * 32;

    // stage x (BN folded) + zero parity-1 h buffers (t=0 reads parity 1).
    for (int i = tid; i < 32 * kT; i += 256) {
      float v = x[(size_t)bm0 * kT + i];
      int m = i / 15, tt = i - m * 15;
      xsf[m * 17 + tt] = v * ws[WS_SS + tt] + ws[WS_SS + 16 + tt];
    }
    for (int i = tid; i < 1024; i += 256) {
      ((unsigned*)h0b[1])[i] = 0u;
      ((unsigned*)h1b[1])[i] = 0u;
    }

    f32x2 c0p[4], c1p[4];   // c-state as row pairs: index mt*2+pr
#pragma unroll
    for (int i = 0; i < 4; ++i) {
      c0p[i] = (f32x2){0.f, 0.f};
      c1p[i] = (f32x2){0.f, 0.f};
    }

    __syncthreads();

#pragma unroll 1
    for (int t = 0; t < kT; ++t) {
      const int p = t & 1;
      const ushort* h0rd = h0b[p ^ 1];
      ushort* h0wr = h0b[p];
      const ushort* h1rd = h1b[p ^ 1];
      ushort* h1wr = h1b[p];

      // ---------------- layer 0: z0' = scaled(b0 + x*w0) + h0_{t-1} @ W ----
      f32x4 acc[2][4];
#pragma unroll
      for (int mt = 0; mt < 2; ++mt)
#pragma unroll
        for (int r = 0; r < 4; ++r) {
          float xv = xsf[(16 * mt + 4 * grp + r) * 17 + t];
#pragma unroll
          for (int j = 0; j < 4; ++j) acc[mt][j][r] = fmaf(xv, w0g[j], b0g[j]);
        }
#pragma unroll
      for (int ks = 0; ks < 2; ++ks) {
        short8 a0 = ldA(h0rd, 0, 32 * ks);
        short8 a1 = ldA(h0rd, 1, 32 * ks);
#pragma unroll
        for (int j = 0; j < 4; ++j) {
          acc[0][j] = __builtin_amdgcn_mfma_f32_16x16x32_bf16(a0, bL0[ks * 4 + j], acc[0][j], 0, 0, 0);
          acc[1][j] = __builtin_amdgcn_mfma_f32_16x16x32_bf16(a1, bL0[ks * 4 + j], acc[1][j], 0, 0, 0);
        }
      }
      // gates L0 (packed row pairs) -> h0wr
#pragma unroll
      for (int mt = 0; mt < 2; ++mt)
#pragma unroll
        for (int pr = 0; pr < 2; ++pr) {
          const int r0 = 2 * pr;
          f32x2 zi = {acc[mt][0][r0], acc[mt][0][r0 + 1]};
          f32x2 zf = {acc[mt][1][r0], acc[mt][1][r0 + 1]};
          f32x2 zg = {acc[mt][2][r0], acc[mt][2][r0 + 1]};
          f32x2 zo = {acc[mt][3][r0], acc[mt][3][r0 + 1]};
          f32x2 h = gatesPK(zi, zf, zg, zo, c0p[mt * 2 + pr]);
          unsigned pk = cvtpk2(h.x, h.y);
          int rowA = 16 * mt + 4 * grp + r0;
          int rowB = rowA + 1;
          h0wr[rowA * 64 + (u ^ ((rowA & 7) << 3))] = (ushort)pk;
          h0wr[rowB * 64 + (u ^ ((rowB & 7) << 3))] = (ushort)(pk >> 16);
        }
      __syncthreads();  // the ONE barrier: h0_t visible for L1

      // ---------------- layer 1: z1' = scaled(b1) + [h0_t; h1_{t-1}] @ W ----
#pragma unroll
      for (int mt = 0; mt < 2; ++mt)
#pragma unroll
        for (int j = 0; j < 4; ++j)
#pragma unroll
          for (int r = 0; r < 4; ++r) acc[mt][j][r] = b1g[j];
#pragma unroll
      for (int ks = 0; ks < 2; ++ks) {
        short8 a0 = ldA(h0wr, 0, 32 * ks);
        short8 a1 = ldA(h0wr, 1, 32 * ks);
#pragma unroll
        for (int j = 0; j < 4; ++j) {
          acc[0][j] = __builtin_amdgcn_mfma_f32_16x16x32_bf16(a0, bL1[ks * 4 + j], acc[0][j], 0, 0, 0);
          acc[1][j] = __builtin_amdgcn_mfma_f32_16x16x32_bf16(a1, bL1[ks * 4 + j], acc[1][j], 0, 0, 0);
        }
      }
#pragma unroll
      for (int ks = 2; ks < 4; ++ks) {
        short8 a0 = ldA(h1rd, 0, 32 * (ks - 2));
        short8 a1 = ldA(h1rd, 1, 32 * (ks - 2));
#pragma unroll
        for (int j = 0; j < 4; ++j) {
          acc[0][j] = __builtin_amdgcn_mfma_f32_16x16x32_bf16(a0, bL1[ks * 4 + j], acc[0][j], 0, 0, 0);
          acc[1][j] = __builtin_amdgcn_mfma_f32_16x16x32_bf16(a1, bL1[ks * 4 + j], acc[1][j], 0, 0, 0);
        }
      }
      // gates L1 (packed row pairs) -> h1wr (or fp32 h1f at t=14)
#pragma unroll
      for (int mt = 0; mt < 2; ++mt)
#pragma unroll
        for (int pr = 0; pr < 2; ++pr) {
          const int r0 = 2 * pr;
          f32x2 zi = {acc[mt][0][r0], acc[mt][0][r0 + 1]};
          f32x2 zf = {acc[mt][1][r0], acc[mt][1][r0 + 1]};
          f32x2 zg = {acc[mt][2][r0], acc[mt][2][r0 + 1]};
          f32x2 zo = {acc[mt][3][r0], acc[mt][3][r0 + 1]};
          f32x2 h = gatesPK(zi, zf, zg, zo, c1p[mt * 2 + pr]);
          int rowA = 16 * mt + 4 * grp + r0;
          int rowB = rowA + 1;
          if (t < kT - 1) {
            unsigned pk = cvtpk2(h.x, h.y);
            h1wr[rowA * 64 + (u ^ ((rowA & 7) << 3))] = (ushort)pk;
            h1wr[rowB * 64 + (u ^ ((rowB & 7) << 3))] = (ushort)(pk >> 16);
          } else {
            h1f[rowA * 68 + u] = h.x;
            h1f[rowB * 68 + u] = h.y;
          }
        }
    }
    __syncthreads();  // h1f visible for FC (also drains last L1-mfma reads)

    // ---------------- FC + exact-erf GELU (fp32) ----------------
    {
      const int o = tid & 63;
      const int ms = tid >> 6;
      float yv[8];
      float fb = fc_b[o];
#pragma unroll
      for (int i = 0; i < 8; ++i) yv[i] = fb;
#pragma unroll 1
      for (int u0 = 0; u0 < 64; u0 += 4) {
        float q0 = ws[WS_FCT + (u0 + 0) * 64 + o];
        float q1 = ws[WS_FCT + (u0 + 1) * 64 + o];
        float q2 = ws[WS_FCT + (u0 + 2) * 64 + o];
        float q3 = ws[WS_FCT + (u0 + 3) * 64 + o];
#pragma unroll
        for (int i = 0; i < 8; ++i) {
          const float4 hq = *(const float4*)&h1f[(ms * 8 + i) * 68 + u0];
          yv[i] = fmaf(hq.x, q0, yv[i]);
          yv[i] = fmaf(hq.y, q1, yv[i]);
          yv[i] = fmaf(hq.z, q2, yv[i]);
          yv[i] = fmaf(hq.w, q3, yv[i]);
        }
      }
#pragma unroll
      for (int i = 0; i < 8; ++i) {
        float v = yv[i];
        float g = 0.5f * v * (1.f + erff(v * 0.70710678118654752f));
        out[(size_t)(bm0 + ms * 8 + i) * 64 + o] = g;
      }
    }
    // no barrier: next tile's staging (h0b[1]/h1b[1]/xsf) is disjoint from
    // h1f/out, and all h-buffer reads ended before the post-loop barrier.
  }
}

extern "C" void kernel_launch(void* const* d_in, const int* in_sizes, int n_in,
                              void* d_out, int out_size, void* d_ws, size_t ws_size,
                              hipStream_t stream) {
  const float* x = (const float*)d_in[0];
  const float* bn_gamma = (const float*)d_in[1];
  const float* bn_beta = (const float*)d_in[2];
  const float* w_ih0 = (const float*)d_in[3];
  const float* w_hh0 = (const float*)d_in[4];
  const float* b_ih0 = (const float*)d_in[5];
  const float* b_hh0 = (const float*)d_in[6];
  const float* w_ih1 = (const float*)d_in[7];
  const float* w_hh1 = (const float*)d_in[8];
  const float* b_ih1 = (const float*)d_in[9];
  const float* b_hh1 = (const float*)d_in[10];
  const float* fc_w = (const float*)d_in[11];
  const float* fc_b = (const float*)d_in[12];
  float* ws = (float*)d_ws;
  float* out = (float*)d_out;

  hipLaunchKernelGGL(prep_kernel, dim3(64), dim3(256), 0, stream,
                     w_hh0, w_ih1, w_hh1, b_ih0, b_hh0, b_ih1, b_hh1, fc_w, ws);
  hipLaunchKernelGGL(bn_sums_kernel, dim3(256), dim3(256), 0, stream, x, ws);
  hipLaunchKernelGGL(bn_final_kernel, dim3(1), dim3(64), 0, stream,
                     bn_gamma, bn_beta, ws);
  hipLaunchKernelGGL(lstm_fused_kernel, dim3(kGrid), dim3(256), 0, stream,
                     x, w_ih0, fc_b, ws, out);
}

// Round 15
// 719.387 us; speedup vs baseline: 2.1560x; 1.0790x over previous
//
#include <hip/hip_runtime.h>
#include <math.h>

// BN(ch=T) -> LSTM(1->64) -> LSTM(64->64) -> FC+GELU.  B=262144 T=15 H=64.
// v15: v14 (776us) + merged-denominator gate math. In exp2 domain with
//      d = 1+2^{z'}:  c = [cp*d_i*d_g + (d_g-2)*d_f] / (d_f*d_i*d_g)  (1 rcp)
//                     h = (d_t-2)/(d_o*d_t)                           (1 rcp)
//      -> 5 exp2 + 2 rcp per gate-slot (was 5+5). Trans ops are quarter-rate,
//      so -3 rcp/slot cuts the dominant VALU cost ~20-30%. Overflow-safe:
//      d <= 2^19 each (|z| bounded by weight scale), Q <= 2^55 < inf.
//
// ws float offsets:
//   WS_SS    0     scale[15]@+0, shift[15]@+16
//   WS_B0    32    scaled b_ih0+b_hh0 [256]
//   WS_B1    288   scaled b_ih1+b_hh1 [256]
//   WS_FCT   1024  fcT[u][o] fp32 [64][64]  (unscaled)
//   WS_STATS 5200  bn sums[15]@+0, sqsums[15]@+16
//   WS_BF    8192  bf16 B-fragments (gate-scaled): 96 chunks x 512 ushort
//     chunk<32:  L0 (w_hh0^T):  ks=chunk>>4 (K=64: 2), nt=chunk&15
//     chunk>=32: L1 ([w_ih1;w_hh1]^T): ks=(chunk-32)>>4 (K=128: 4), nt=&15
//     elem(lane,j) = B[k=32*ks+8*(lane>>4)+j][n=16*nt+(lane&15)]

typedef __attribute__((ext_vector_type(8))) short short8;
typedef __attribute__((ext_vector_type(4))) float f32x4;
typedef __attribute__((ext_vector_type(2))) float f32x2;

namespace {
constexpr int kB = 262144;
constexpr int kT = 15;
constexpr int kTiles = kB / 32;   // 8192
constexpr int kGrid = 512;        // 2 blocks per CU; 16 tiles per block
constexpr int WS_SS = 0;
constexpr int WS_B0 = 32;
constexpr int WS_B1 = 288;
constexpr int WS_FCT = 1024;
constexpr int WS_STATS = 5200;
constexpr int WS_BF = 8192;
}  // namespace

#if __has_builtin(__builtin_amdgcn_exp2f)
__device__ __forceinline__ float exp2x(float x) {
  return __builtin_amdgcn_exp2f(x);
}
#else
__device__ __forceinline__ float exp2x(float x) {
  float r;
  asm("v_exp_f32 %0, %1\n\ts_nop 1" : "=v"(r) : "v"(x));
  return r;
}
#endif

__device__ __forceinline__ ushort f2bf(float f) {
  unsigned u = __float_as_uint(f);
  unsigned r = (u + 0x7fffu + ((u >> 16) & 1u)) >> 16;  // RNE
  return (ushort)r;
}
// pack two f32 -> two bf16 in one u32 (RNE), single HW instr
__device__ __forceinline__ unsigned cvtpk2(float lo, float hi) {
  unsigned r;
  asm("v_cvt_pk_bf16_f32 %0, %1, %2" : "=v"(r) : "v"(lo), "v"(hi));
  return r;
}
// gate scale for gate index g (0=i,1=f,2=g,3=o): sigmoid gates get -log2e
// (folds exp(-z) negation), tanh gate gets +2log2e (tanh(x)=1-2/(1+e^{2x}))
__device__ __forceinline__ float gscale(int g) {
  return (g == 2) ? 2.88539008177792681472f : -1.44269504088896340736f;
}

__global__ void prep_kernel(const float* __restrict__ w_hh0,
                            const float* __restrict__ w_ih1,
                            const float* __restrict__ w_hh1,
                            const float* __restrict__ b_ih0,
                            const float* __restrict__ b_hh0,
                            const float* __restrict__ b_ih1,
                            const float* __restrict__ b_hh1,
                            const float* __restrict__ fc_w,
                            float* __restrict__ ws) {
  const int stride = gridDim.x * blockDim.x;
  const int t0 = blockIdx.x * blockDim.x + threadIdx.x;
  ushort* bf = (ushort*)(ws + WS_BF);
  for (int i = t0; i < 96 * 512; i += stride) {
    int chunk = i >> 9, lane = (i >> 3) & 63, j = i & 7;
    float v;
    int n;
    if (chunk < 32) {
      int ks = chunk >> 4, nt = chunk & 15;
      int k = 32 * ks + 8 * (lane >> 4) + j;
      n = 16 * nt + (lane & 15);
      v = w_hh0[n * 64 + k];
    } else {
      int c2 = chunk - 32;
      int ks = c2 >> 4, nt = c2 & 15;
      int k = 32 * ks + 8 * (lane >> 4) + j;
      n = 16 * nt + (lane & 15);
      v = (k < 64) ? w_ih1[n * 64 + k] : w_hh1[n * 64 + (k - 64)];
    }
    bf[i] = f2bf(v * gscale(n >> 6));
  }
  for (int i = t0; i < 4096; i += stride) {
    int u = i >> 6, o = i & 63;
    ws[WS_FCT + i] = fc_w[o * 64 + u];
  }
  for (int i = t0; i < 256; i += stride) {
    float sc = gscale(i >> 6);
    ws[WS_B0 + i] = (b_ih0[i] + b_hh0[i]) * sc;
    ws[WS_B1 + i] = (b_ih1[i] + b_hh1[i]) * sc;
  }
  for (int i = t0; i < 32; i += stride) ws[WS_STATS + i] = 0.f;
}

// Each thread owns one chunk of 15 consecutive float4s (60 elems = 4 full
// mod-15 periods, chunk-aligned so t-indices are compile-time constants).
__global__ void bn_sums_kernel(const float* __restrict__ x,
                               float* __restrict__ ws) {
  __shared__ float ls[16], lq[16];
  const int tid = threadIdx.x;
  if (tid < 16) { ls[tid] = 0.f; lq[tid] = 0.f; }
  __syncthreads();
  const float4* x4 = (const float4*)x;
  const int c0 = (blockIdx.x * 256 + tid) * 15;
  float s[15], q[15];
#pragma unroll
  for (int t = 0; t < 15; ++t) { s[t] = 0.f; q[t] = 0.f; }
#pragma unroll
  for (int c = 0; c < 15; ++c) {
    float4 v = x4[c0 + c];
    s[(4 * c + 0) % 15] += v.x; q[(4 * c + 0) % 15] += v.x * v.x;
    s[(4 * c + 1) % 15] += v.y; q[(4 * c + 1) % 15] += v.y * v.y;
    s[(4 * c + 2) % 15] += v.z; q[(4 * c + 2) % 15] += v.z * v.z;
    s[(4 * c + 3) % 15] += v.w; q[(4 * c + 3) % 15] += v.w * v.w;
  }
#pragma unroll
  for (int t = 0; t < 15; ++t) {
    atomicAdd(&ls[t], s[t]);
    atomicAdd(&lq[t], q[t]);
  }
  __syncthreads();
  if (tid < 15) {
    atomicAdd(&ws[WS_STATS + tid], ls[tid]);
    atomicAdd(&ws[WS_STATS + 16 + tid], lq[tid]);
  }
}

__global__ void bn_final_kernel(const float* __restrict__ gamma,
                                const float* __restrict__ beta,
                                float* __restrict__ ws) {
  int t = threadIdx.x;
  if (t < 15) {
    const float inv = 1.f / (float)kB;
    float mean = ws[WS_STATS + t] * inv;
    float var = ws[WS_STATS + 16 + t] * inv - mean * mean;
    float sc = gamma[t] * rsqrtf(var + 1e-5f);
    ws[WS_SS + t] = sc;
    ws[WS_SS + 16 + t] = beta[t] - mean * sc;
  }
}

__global__ __launch_bounds__(256, 2) void lstm_fused_kernel(
    const float* __restrict__ x, const float* __restrict__ w_ih0,
    const float* __restrict__ fc_b, const float* __restrict__ ws,
    float* __restrict__ out) {
  // h0b/h1b: [parity][row][unit] ushort, XOR-swizzled rows (64-ushort rows)
  __shared__ ushort h0b[2][32 * 64];   // 8 KB
  __shared__ ushort h1b[2][32 * 64];   // 8 KB
  __shared__ float xsf[32 * 17];       // 2.2 KB
  __shared__ float h1f[32 * 68];       // 8.7 KB

  const int tid = threadIdx.x;
  const int lane = tid & 63;
  const int wv = tid >> 6;
  const int grp = lane >> 4;
  const int l15 = lane & 15;
  const int u = wv * 16 + l15;

  // ---- per-block one-time hoists ----
  float b0g[4], b1g[4], w0g[4];
#pragma unroll
  for (int j = 0; j < 4; ++j) {
    b0g[j] = ws[WS_B0 + u + 64 * j];
    b1g[j] = ws[WS_B1 + u + 64 * j];
    w0g[j] = w_ih0[u + 64 * j] * gscale(j);
  }
  const short8* bfr = (const short8*)(ws + WS_BF);
  short8 bL0[8], bL1[16];
#pragma unroll
  for (int ks = 0; ks < 2; ++ks)
#pragma unroll
    for (int j = 0; j < 4; ++j)
      bL0[ks * 4 + j] = bfr[(ks * 16 + wv + 4 * j) * 64 + lane];
#pragma unroll
  for (int ks = 0; ks < 4; ++ks)
#pragma unroll
    for (int j = 0; j < 4; ++j)
      bL1[ks * 4 + j] = bfr[(32 + ks * 16 + wv + 4 * j) * 64 + lane];

  // A-fragment read: rows 0..15 (+16*mt), k-slice base kbase+8*grp, XOR swz
  auto ldA = [&](const ushort* buf, int mt, int kbase) -> short8 {
    int row = l15 + 16 * mt;
    int off = (kbase + 8 * grp) ^ ((row & 7) << 3);
    return *(const short8*)&buf[row * 64 + off];
  };

  // packed gates on one row-pair, merged denominators (2 rcp per slot):
  //   d = 1+2^{z'};  c = (cp*d_i*d_g + (d_g-2)*d_f) / (d_f*d_i*d_g)
  //   h = (d_t-2)/(d_o*d_t),  d_t = 1+2^{2c*log2e}
  auto gatesPK = [&](f32x2 zi, f32x2 zf, f32x2 zg, f32x2 zo,
                     f32x2& cp) -> f32x2 {
    f32x2 ei, ef, eg, eo;
    ei.x = exp2x(zi.x); ei.y = exp2x(zi.y);
    ef.x = exp2x(zf.x); ef.y = exp2x(zf.y);
    eg.x = exp2x(zg.x); eg.y = exp2x(zg.y);
    eo.x = exp2x(zo.x); eo.y = exp2x(zo.y);
    f32x2 di = ei + 1.f;               // v_pk_add_f32
    f32x2 df = ef + 1.f;
    f32x2 dg = eg + 1.f;
    f32x2 dd = eo + 1.f;
    f32x2 P = di * dg;                 // pk_mul
    f32x2 Q = P * df;                  // pk_mul  (<= 2^55, no overflow)
    f32x2 num = cp * P + (dg - 2.f) * df;  // pk ops
    f32x2 rq;
    rq.x = __builtin_amdgcn_rcpf(Q.x);
    rq.y = __builtin_amdgcn_rcpf(Q.y);
    f32x2 c = num * rq;
    cp = c;
    f32x2 et;
    et.x = exp2x(c.x * 2.88539008177792681472f);
    et.y = exp2x(c.y * 2.88539008177792681472f);
    f32x2 dt = et + 1.f;
    f32x2 R = dd * dt;
    f32x2 rr;
    rr.x = __builtin_amdgcn_rcpf(R.x);
    rr.y = __builtin_amdgcn_rcpf(R.y);
    return (dt - 2.f) * rr;
  };

#pragma unroll 1
  for (int tile = blockIdx.x; tile < kTiles; tile += kGrid) {
    const int bm0 = tile * 32;

    // stage x (BN folded) + zero parity-1 h buffers (t=0 reads parity 1).
    for (int i = tid; i < 32 * kT; i += 256) {
      float v = x[(size_t)bm0 * kT + i];
      int m = i / 15, tt = i - m * 15;
      xsf[m * 17 + tt] = v * ws[WS_SS + tt] + ws[WS_SS + 16 + tt];
    }
    for (int i = tid; i < 1024; i += 256) {
      ((unsigned*)h0b[1])[i] = 0u;
      ((unsigned*)h1b[1])[i] = 0u;
    }

    f32x2 c0p[4], c1p[4];   // c-state as row pairs: index mt*2+pr
#pragma unroll
    for (int i = 0; i < 4; ++i) {
      c0p[i] = (f32x2){0.f, 0.f};
      c1p[i] = (f32x2){0.f, 0.f};
    }

    __syncthreads();

#pragma unroll 1
    for (int t = 0; t < kT; ++t) {
      const int p = t & 1;
      const ushort* h0rd = h0b[p ^ 1];
      ushort* h0wr = h0b[p];
      const ushort* h1rd = h1b[p ^ 1];
      ushort* h1wr = h1b[p];

      // ---------------- layer 0: z0' = scaled(b0 + x*w0) + h0_{t-1} @ W ----
      f32x4 acc[2][4];
#pragma unroll
      for (int mt = 0; mt < 2; ++mt)
#pragma unroll
        for (int r = 0; r < 4; ++r) {
          float xv = xsf[(16 * mt + 4 * grp + r) * 17 + t];
#pragma unroll
          for (int j = 0; j < 4; ++j) acc[mt][j][r] = fmaf(xv, w0g[j], b0g[j]);
        }
#pragma unroll
      for (int ks = 0; ks < 2; ++ks) {
        short8 a0 = ldA(h0rd, 0, 32 * ks);
        short8 a1 = ldA(h0rd, 1, 32 * ks);
#pragma unroll
        for (int j = 0; j < 4; ++j) {
          acc[0][j] = __builtin_amdgcn_mfma_f32_16x16x32_bf16(a0, bL0[ks * 4 + j], acc[0][j], 0, 0, 0);
          acc[1][j] = __builtin_amdgcn_mfma_f32_16x16x32_bf16(a1, bL0[ks * 4 + j], acc[1][j], 0, 0, 0);
        }
      }
      // gates L0 (packed row pairs) -> h0wr
#pragma unroll
      for (int mt = 0; mt < 2; ++mt)
#pragma unroll
        for (int pr = 0; pr < 2; ++pr) {
          const int r0 = 2 * pr;
          f32x2 zi = {acc[mt][0][r0], acc[mt][0][r0 + 1]};
          f32x2 zf = {acc[mt][1][r0], acc[mt][1][r0 + 1]};
          f32x2 zg = {acc[mt][2][r0], acc[mt][2][r0 + 1]};
          f32x2 zo = {acc[mt][3][r0], acc[mt][3][r0 + 1]};
          f32x2 h = gatesPK(zi, zf, zg, zo, c0p[mt * 2 + pr]);
          unsigned pk = cvtpk2(h.x, h.y);
          int rowA = 16 * mt + 4 * grp + r0;
          int rowB = rowA + 1;
          h0wr[rowA * 64 + (u ^ ((rowA & 7) << 3))] = (ushort)pk;
          h0wr[rowB * 64 + (u ^ ((rowB & 7) << 3))] = (ushort)(pk >> 16);
        }
      __syncthreads();  // the ONE barrier: h0_t visible for L1

      // ---------------- layer 1: z1' = scaled(b1) + [h0_t; h1_{t-1}] @ W ----
#pragma unroll
      for (int mt = 0; mt < 2; ++mt)
#pragma unroll
        for (int j = 0; j < 4; ++j)
#pragma unroll
          for (int r = 0; r < 4; ++r) acc[mt][j][r] = b1g[j];
#pragma unroll
      for (int ks = 0; ks < 2; ++ks) {
        short8 a0 = ldA(h0wr, 0, 32 * ks);
        short8 a1 = ldA(h0wr, 1, 32 * ks);
#pragma unroll
        for (int j = 0; j < 4; ++j) {
          acc[0][j] = __builtin_amdgcn_mfma_f32_16x16x32_bf16(a0, bL1[ks * 4 + j], acc[0][j], 0, 0, 0);
          acc[1][j] = __builtin_amdgcn_mfma_f32_16x16x32_bf16(a1, bL1[ks * 4 + j], acc[1][j], 0, 0, 0);
        }
      }
#pragma unroll
      for (int ks = 2; ks < 4; ++ks) {
        short8 a0 = ldA(h1rd, 0, 32 * (ks - 2));
        short8 a1 = ldA(h1rd, 1, 32 * (ks - 2));
#pragma unroll
        for (int j = 0; j < 4; ++j) {
          acc[0][j] = __builtin_amdgcn_mfma_f32_16x16x32_bf16(a0, bL1[ks * 4 + j], acc[0][j], 0, 0, 0);
          acc[1][j] = __builtin_amdgcn_mfma_f32_16x16x32_bf16(a1, bL1[ks * 4 + j], acc[1][j], 0, 0, 0);
        }
      }
      // gates L1 (packed row pairs) -> h1wr (or fp32 h1f at t=14)
#pragma unroll
      for (int mt = 0; mt < 2; ++mt)
#pragma unroll
        for (int pr = 0; pr < 2; ++pr) {
          const int r0 = 2 * pr;
          f32x2 zi = {acc[mt][0][r0], acc[mt][0][r0 + 1]};
          f32x2 zf = {acc[mt][1][r0], acc[mt][1][r0 + 1]};
          f32x2 zg = {acc[mt][2][r0], acc[mt][2][r0 + 1]};
          f32x2 zo = {acc[mt][3][r0], acc[mt][3][r0 + 1]};
          f32x2 h = gatesPK(zi, zf, zg, zo, c1p[mt * 2 + pr]);
          int rowA = 16 * mt + 4 * grp + r0;
          int rowB = rowA + 1;
          if (t < kT - 1) {
            unsigned pk = cvtpk2(h.x, h.y);
            h1wr[rowA * 64 + (u ^ ((rowA & 7) << 3))] = (ushort)pk;
            h1wr[rowB * 64 + (u ^ ((rowB & 7) << 3))] = (ushort)(pk >> 16);
          } else {
            h1f[rowA * 68 + u] = h.x;
            h1f[rowB * 68 + u] = h.y;
          }
        }
    }
    __syncthreads();  // h1f visible for FC (also drains last L1-mfma reads)

    // ---------------- FC + exact-erf GELU (fp32) ----------------
    {
      const int o = tid & 63;
      const int ms = tid >> 6;
      float yv[8];
      float fb = fc_b[o];
#pragma unroll
      for (int i = 0; i < 8; ++i) yv[i] = fb;
#pragma unroll 1
      for (int u0 = 0; u0 < 64; u0 += 4) {
        float q0 = ws[WS_FCT + (u0 + 0) * 64 + o];
        float q1 = ws[WS_FCT + (u0 + 1) * 64 + o];
        float q2 = ws[WS_FCT + (u0 + 2) * 64 + o];
        float q3 = ws[WS_FCT + (u0 + 3) * 64 + o];
#pragma unroll
        for (int i = 0; i < 8; ++i) {
          const float4 hq = *(const float4*)&h1f[(ms * 8 + i) * 68 + u0];
          yv[i] = fmaf(hq.x, q0, yv[i]);
          yv[i] = fmaf(hq.y, q1, yv[i]);
          yv[i] = fmaf(hq.z, q2, yv[i]);
          yv[i] = fmaf(hq.w, q3, yv[i]);
        }
      }
#pragma unroll
      for (int i = 0; i < 8; ++i) {
        float v = yv[i];
        float g = 0.5f * v * (1.f + erff(v * 0.70710678118654752f));
        out[(size_t)(bm0 + ms * 8 + i) * 64 + o] = g;
      }
    }
    // no barrier: next tile's staging (h0b[1]/h1b[1]/xsf) is disjoint from
    // h1f/out, and all h-buffer reads ended before the post-loop barrier.
  }
}

extern "C" void kernel_launch(void* const* d_in, const int* in_sizes, int n_in,
                              void* d_out, int out_size, void* d_ws, size_t ws_size,
                              hipStream_t stream) {
  const float* x = (const float*)d_in[0];
  const float* bn_gamma = (const float*)d_in[1];
  const float* bn_beta = (const float*)d_in[2];
  const float* w_ih0 = (const float*)d_in[3];
  const float* w_hh0 = (const float*)d_in[4];
  const float* b_ih0 = (const float*)d_in[5];
  const float* b_hh0 = (const float*)d_in[6];
  const float* w_ih1 = (const float*)d_in[7];
  const float* w_hh1 = (const float*)d_in[8];
  const float* b_ih1 = (const float*)d_in[9];
  const float* b_hh1 = (const float*)d_in[10];
  const float* fc_w = (const float*)d_in[11];
  const float* fc_b = (const float*)d_in[12];
  float* ws = (float*)d_ws;
  float* out = (float*)d_out;

  hipLaunchKernelGGL(prep_kernel, dim3(64), dim3(256), 0, stream,
                     w_hh0, w_ih1, w_hh1, b_ih0, b_hh0, b_ih1, b_hh1, fc_w, ws);
  hipLaunchKernelGGL(bn_sums_kernel, dim3(256), dim3(256), 0, stream, x, ws);
  hipLaunchKernelGGL(bn_final_kernel, dim3(1), dim3(64), 0, stream,
                     bn_gamma, bn_beta, ws);
  hipLaunchKernelGGL(lstm_fused_kernel, dim3(kGrid), dim3(256), 0, stream,
                     x, w_ih0, fc_b, ws, out);
}